// Round 3
// baseline (8071.490 us; speedup 1.0000x reference)
//
#include <hip/hip_runtime.h>

#define NB 32
#define NT 512
#define NI 512
#define NH 512
#define NG 2048
#define GH (NG*NH)
#define BTH ((size_t)NB*NT*NH)   // 8388608
#define BH  (NB*NH)              // 16384

typedef unsigned int uint;
typedef unsigned long long u64;
typedef _Float16 v2h __attribute__((ext_vector_type(2)));
typedef _Float16 f16x4 __attribute__((ext_vector_type(4)));
typedef _Float16 f16x8 __attribute__((ext_vector_type(8)));
typedef float f32x4 __attribute__((ext_vector_type(4)));
union un8 { f16x4 h[2]; f16x8 v; };

// ---- ws layout (bytes) ----
#define OFF_XPROJ 0
#define SZ_XPROJ  ((size_t)NB*NT*NG*2)            // 64 MB  x_proj bf16 [B][T][G]
#define OFF_BIAS  (OFF_XPROJ + SZ_XPROJ)
#define SZ_BIAS   ((size_t)NB*NG*4)               // 256 KB fp32 bias [B][G]
#define OFF_HP    (OFF_BIAS + SZ_BIAS)
#define SZ_HP     ((size_t)2*NB*512*4)            // 128 KB tagged {tag16|f16} words, dbuf

__device__ __forceinline__ float bf2f(unsigned short u) {
    union { uint i; float f; } v; v.i = ((uint)u) << 16; return v.f;
}
__device__ __forceinline__ unsigned short f2bf(float f) {
    union { uint i; float f; } v; v.f = f;
    uint r = v.i + 0x7FFFu + ((v.i >> 16) & 1u);
    return (unsigned short)(r >> 16);
}
__device__ __forceinline__ uint pkf16(float a, float b) {
    auto p = __builtin_amdgcn_cvt_pkrtz(a, b);   // __fp16 ext_vector(2)
    return __builtin_bit_cast(uint, p);
}
__device__ __forceinline__ float dot2(uint wu, uint hu, float c) {
#if __has_builtin(__builtin_amdgcn_fdot2)
    return __builtin_amdgcn_fdot2(__builtin_bit_cast(v2h, wu),
                                  __builtin_bit_cast(v2h, hu), c, false);
#else
    v2h a = __builtin_bit_cast(v2h, wu), b = __builtin_bit_cast(v2h, hu);
    return c + (float)a[0] * (float)b[0] + (float)a[1] * (float)b[1];
#endif
}
// z = clip(1.2*sigmoid(1.5*(log(eps)-log(1-eps)+m)) - 0.1, 0, 1)
__device__ __forceinline__ float gate_z(float eps, float m) {
    float u = (__logf(eps) - __logf(1.0f - eps) + m) * 1.5f;
    float y = 1.0f / (1.0f + __expf(-u));
    float z = fmaf(y, 1.2f, -0.1f);
    return fminf(fmaxf(z, 0.0f), 1.0f);
}
__device__ __forceinline__ float sigmoidf_(float x) {
    return 1.0f / (1.0f + __expf(-x));
}
__device__ __forceinline__ float tanhf_(float x) {
    return 1.0f - 2.0f / (__expf(2.0f * x) + 1.0f);
}
// k-index XOR swizzle for xproj LDS tiles (rows stride 512 f16 = bank-degenerate)
__device__ __forceinline__ int kswz(int row, int k) {
    return k ^ ((row & 7) << 2);
}
// hsh physical uint index for logical f16-pair p: 2-way max aliasing on 16B reads
__device__ __forceinline__ int pswz(int p) {
    return (p & ~15) | (((((p >> 2) & 3) ^ ((p >> 5) & 3)) << 2) | (p & 3));
}

// ---------- bias[b][g] ----------
__global__ __launch_bounds__(256) void k_bias(
    const float* __restrict__ eb1, const float* __restrict__ eb2,
    const float* __restrict__ mb1, const float* __restrict__ mb2,
    const float* __restrict__ b1, const float* __restrict__ b2,
    float* __restrict__ bias) {
    int idx = blockIdx.x * 256 + threadIdx.x;
    int g = idx & (NG - 1);
    bias[idx] = gate_z(eb1[idx], mb1[g]) * b1[g] + gate_z(eb2[idx], mb2[g]) * b2[g];
}

// ---------- x_proj[b][t][g], f16 MFMA ----------
__global__ __launch_bounds__(512, 2) void k_xproj(
    const float* __restrict__ seq, const float* __restrict__ eps_ih,
    const float* __restrict__ mask_ih, const float* __restrict__ w_ih,
    const float* __restrict__ bias, unsigned short* __restrict__ xproj) {
    __shared__ _Float16 Wl[64][512];   // [g][k swizzled]  64 KB
    __shared__ _Float16 Al[64][512];   // [t][k swizzled]  64 KB
    int g0 = blockIdx.x << 6;
    int b  = blockIdx.y;
    int tid = threadIdx.x;
    int w = tid >> 6, lane = tid & 63;
    int lr = lane & 15, lg = lane >> 4;
    int mo = (w & 3) << 4, no = (w >> 2) << 5;

    // ---- stage gated W (once) ----
    {
        int g = tid >> 3, k0 = (tid & 7) << 6;
        size_t moff = (size_t)(g0 + g) * NI + k0;
        const float4* ep = (const float4*)(eps_ih + (size_t)b * GH + moff);
        const float4* mp = (const float4*)(mask_ih + moff);
        const float4* wp = (const float4*)(w_ih + moff);
#pragma unroll
        for (int q = 0; q < 16; ++q) {
            float4 e = ep[q], m = mp[q], wv = wp[q];
            f16x4 o;
            o[0] = (_Float16)(gate_z(e.x, m.x) * wv.x);
            o[1] = (_Float16)(gate_z(e.y, m.y) * wv.y);
            o[2] = (_Float16)(gate_z(e.z, m.z) * wv.z);
            o[3] = (_Float16)(gate_z(e.w, m.w) * wv.w);
            *(f16x4*)&Wl[g][kswz(g, k0 + (q << 2))] = o;
        }
    }

    float bs0 = bias[b * NG + g0 + no + lr];
    float bs1 = bias[b * NG + g0 + no + 16 + lr];
    int ra = mo + lr, rb0 = no + lr, rb1 = no + 16 + lr;

    for (int tc = 0; tc < NT; tc += 64) {
        // ---- stage A chunk (fp32 seq -> f16) ----
        {
            int r = tid >> 3, k0 = (tid & 7) << 6;
            const float4* sp = (const float4*)(seq + (size_t)(b * NT + tc + r) * NI + k0);
#pragma unroll
            for (int q = 0; q < 16; ++q) {
                float4 v = sp[q];
                f16x4 o;
                o[0] = (_Float16)v.x; o[1] = (_Float16)v.y;
                o[2] = (_Float16)v.z; o[3] = (_Float16)v.w;
                *(f16x4*)&Al[r][kswz(r, k0 + (q << 2))] = o;
            }
        }
        __syncthreads();

        f32x4 acc0 = {0.f, 0.f, 0.f, 0.f}, acc1 = {0.f, 0.f, 0.f, 0.f};
#pragma unroll
        for (int i0 = 0; i0 < NI; i0 += 32) {
            int k0 = i0 + (lg << 2);
            un8 a, b0, b1;
            a.h[0]  = *(const f16x4*)&Al[ra][kswz(ra, k0)];
            a.h[1]  = *(const f16x4*)&Al[ra][kswz(ra, k0 + 16)];
            b0.h[0] = *(const f16x4*)&Wl[rb0][kswz(rb0, k0)];
            b0.h[1] = *(const f16x4*)&Wl[rb0][kswz(rb0, k0 + 16)];
            b1.h[0] = *(const f16x4*)&Wl[rb1][kswz(rb1, k0)];
            b1.h[1] = *(const f16x4*)&Wl[rb1][kswz(rb1, k0 + 16)];
            acc0 = __builtin_amdgcn_mfma_f32_16x16x32_f16(a.v, b0.v, acc0, 0, 0, 0);
            acc1 = __builtin_amdgcn_mfma_f32_16x16x32_f16(a.v, b1.v, acc1, 0, 0, 0);
        }
        // ---- epilogue: +bias, bf16 store. C/D: col=lane&15, row=(lane>>4)*4+reg
#pragma unroll
        for (int r = 0; r < 4; ++r) {
            int t = tc + mo + (lg << 2) + r;
            unsigned short* op = xproj + ((size_t)(b * NT + t) << 11) + g0 + no + lr;
            op[0]  = f2bf(acc0[r] + bs0);
            op[16] = f2bf(acc1[r] + bs1);
        }
        __syncthreads();   // Al WAR guard before next chunk's staging
    }
}

// ---------- Persistent recurrence: weights resident in VGPRs ----------
// 256 blocks x 1024 threads, 1 block/CU. SLICE-MAJOR block id: bb = slice*32 + b
// so all 8 slices of batch b satisfy bb%8 == b%8 -> same XCD under the measured
// round-robin block->XCD mapping -> exchange lives in that XCD's shared L2.
// h exchange word: {tag16 = t+1 | f16(h)} per j, double-buffered by parity.
// Producer: agent-scope store (MALL publish, placement-robust fallback) FIRST,
// then sc0 store (write-through to shared L2 = fast path). Consumer: sc0 poll
// loop (L1-bypassed, L2-hit ~200cy), every 16th iteration an agent-scope load
// (picks value from MALL if blocks ever land on different XCDs -> never hangs).
// Barrier: raw s_barrier with lgkmcnt(0) only -- no vmcnt drain of out-stores.
__global__ __launch_bounds__(1024, 4) void k_recur(
    const float* __restrict__ eps, const float* __restrict__ mask,
    const float* __restrict__ w, const unsigned short* __restrict__ xproj,
    uint* __restrict__ hpk, float* __restrict__ out) {
    __shared__ uint hsh[2][256];   // double-buffered packed f16 h pairs (swizzled)
    int bb = blockIdx.x;
    int b = bb & 31, slice = bb >> 5;
    int tid = threadIdx.x;
    int wv = tid >> 6, lane = tid & 63;
    int jj = lane >> 4, kg = lane & 15;
    int j = (slice << 6) + (wv << 2) + jj;
    bool leader = (kg == 0);
    int gsel = kg & 3;

    // ---- one-time: load + gate + f16-pack weights into registers ----
    uint wreg[4][16];
#pragma unroll
    for (int q = 0; q < 4; ++q) {
        size_t off = (size_t)((q << 9) + j) * NH + (kg << 5);
        const float2* ep = (const float2*)(eps + (size_t)b * GH + off);
        const float2* mp = (const float2*)(mask + off);
        const float2* wp = (const float2*)(w + off);
#pragma unroll
        for (int u = 0; u < 16; ++u) {
            float2 e = ep[u], m = mp[u], ww = wp[u];
            wreg[q][u] = pkf16(gate_z(e.x, m.x) * ww.x,
                               gate_z(e.y, m.y) * ww.y);
        }
    }

    // prefetch xproj for t=0: lane kg<4 loads its own gate's addend
    float xp = 0.f;
    if (kg < 4) {
        const unsigned short* xq = xproj + ((size_t)(b * NT) << 11) + j + (gsel << 9);
        xp = bf2f(xq[0]);
    }

    float c = 0.0f;
    for (int t = 0; t < NT; ++t) {
        int par = t & 1;
        // ---- stage h: poll tagged words (sc0 fast path, agent fallback) ----
        if (tid < 256 && !(t > 0 && (tid >> 5) == slice)) {
            const uint* src = hpk + ((size_t)(par * NB + b) << 9) + (tid << 1);
            uint lo, hi;
            int it = 0;
            for (;;) {
                if ((++it & 15) == 0) {
                    u64 a = __hip_atomic_load((const u64*)src, __ATOMIC_RELAXED,
                                              __HIP_MEMORY_SCOPE_AGENT);
                    lo = (uint)a; hi = (uint)(a >> 32);
                } else {
                    u64 a;
                    asm volatile("global_load_dwordx2 %0, %1, off sc0\n\t"
                                 "s_waitcnt vmcnt(0)"
                                 : "=v"(a) : "v"(src) : "memory");
                    lo = (uint)a; hi = (uint)(a >> 32);
                }
                if ((lo >> 16) == (uint)t && (hi >> 16) == (uint)t) break;
            }
            hsh[par][pswz(tid)] = (lo & 0xffffu) | (hi << 16);
        }
        // raw barrier: LDS ordering only, no vmcnt drain of out/h stores
        asm volatile("s_waitcnt lgkmcnt(0)\n\ts_barrier" ::: "memory");
        __builtin_amdgcn_sched_barrier(0);

        float a0 = 0.f, a1 = 0.f, a2 = 0.f, a3 = 0.f;
#pragma unroll
        for (int r = 0; r < 4; ++r) {
            uint4 hv = *(const uint4*)&hsh[par][(kg << 4) | ((r ^ ((kg >> 1) & 3)) << 2)];
            uint hu[4] = {hv.x, hv.y, hv.z, hv.w};
#pragma unroll
            for (int u = 0; u < 4; ++u) {
                a0 = dot2(wreg[0][(r << 2) + u], hu[u], a0);
                a1 = dot2(wreg[1][(r << 2) + u], hu[u], a1);
                a2 = dot2(wreg[2][(r << 2) + u], hu[u], a2);
                a3 = dot2(wreg[3][(r << 2) + u], hu[u], a3);
            }
        }
        // ---- swap-butterfly reduce: 11 shfls; lane kg ends with gate (kg&3) ----
        a0 += __shfl_xor(a0, 8);
        a1 += __shfl_xor(a1, 8);
        a2 += __shfl_xor(a2, 8);
        a3 += __shfl_xor(a3, 8);
        a0 += __shfl_xor(a0, 4);
        a1 += __shfl_xor(a1, 4);
        a2 += __shfl_xor(a2, 4);
        a3 += __shfl_xor(a3, 4);
        bool hi2 = (kg & 2) != 0;
        float s0 = hi2 ? a0 : a2, s1 = hi2 ? a1 : a3;
        float k0 = hi2 ? a2 : a0, k1 = hi2 ? a3 : a1;
        k0 += __shfl_xor(s0, 2);
        k1 += __shfl_xor(s1, 2);
        bool hi1 = (kg & 1) != 0;
        float ss = hi1 ? k0 : k1;
        float S = (hi1 ? k1 : k0) + __shfl_xor(ss, 1);
        // ---- activation on lane gsel (uniform) ----
        float x = S + xp;
        float y = sigmoidf_(gsel == 2 ? 2.0f * x : x);
        float act = gsel == 2 ? fmaf(y, 2.0f, -1.0f) : y;
        float af_ = __shfl(act, (lane & 48) | 1);
        float ag_ = __shfl(act, (lane & 48) | 2);
        float ao_ = __shfl(act, (lane & 48) | 3);
        if (leader) {
            c = fmaf(af_, c, act * ag_);   // act on leader = i-gate
            float h = ao_ * tanhf_(c);
            unsigned short hb = __builtin_bit_cast(unsigned short, (_Float16)h);
            uint word = ((uint)(t + 1) << 16) | (uint)hb;
            uint* dst = hpk + ((size_t)((par ^ 1) * NB + b) << 9) + j;
            // MALL publish first (fallback path), then L2 fast-path store
            __hip_atomic_store(dst, word, __ATOMIC_RELAXED, __HIP_MEMORY_SCOPE_AGENT);
            asm volatile("global_store_dword %0, %1, off sc0"
                         :: "v"(dst), "v"(word) : "memory");
            // local shortcut: own f16 straight into next LDS buffer
            ((unsigned short*)&hsh[par ^ 1][pswz(j >> 1)])[j & 1] = hb;
            out[((size_t)(b * NT + t) << 9) + j] = h;
            if (t == NT - 1) {
                out[BTH + (size_t)(b << 9) + j] = h;
                out[BTH + BH + (size_t)(b << 9) + j] = c;
            }
        }
        // prefetch xproj for t+1 (off the critical path; absorbed by next poll)
        if (kg < 4 && t + 1 < NT) {
            const unsigned short* xq =
                xproj + ((size_t)(b * NT + t + 1) << 11) + j + (gsel << 9);
            xp = bf2f(xq[0]);
        }
    }
}

extern "C" void kernel_launch(void* const* d_in, const int* in_sizes, int n_in,
                              void* d_out, int out_size, void* d_ws, size_t ws_size,
                              hipStream_t stream) {
    const float* seq      = (const float*)d_in[0];
    const float* w_ih     = (const float*)d_in[1];
    const float* w_hh     = (const float*)d_in[2];
    const float* b_ih     = (const float*)d_in[3];
    const float* b_hh     = (const float*)d_in[4];
    const float* mask_ih  = (const float*)d_in[5];
    const float* mask_hh  = (const float*)d_in[6];
    const float* mask_bih = (const float*)d_in[7];
    const float* mask_bhh = (const float*)d_in[8];
    const float* eps_ih   = (const float*)d_in[9];
    const float* eps_hh   = (const float*)d_in[10];
    const float* eps_bih  = (const float*)d_in[11];
    const float* eps_bhh  = (const float*)d_in[12];

    char* ws = (char*)d_ws;
    unsigned short* xproj = (unsigned short*)(ws + OFF_XPROJ);
    float* bias  = (float*)(ws + OFF_BIAS);
    uint*  hpk   = (uint*)(ws + OFF_HP);
    float* out   = (float*)d_out;

    // zero BOTH parity buffers each launch: t=0 expects tag 0 (h0=0), and no
    // stale tag from a previous run can ever match (cross-run race removed).
    (void)hipMemsetAsync(hpk, 0, SZ_HP, stream);

    k_bias<<<dim3(256), dim3(256), 0, stream>>>(eps_bih, eps_bhh, mask_bih, mask_bhh,
                                                b_ih, b_hh, bias);
    k_xproj<<<dim3(NG / 64, NB), dim3(512), 0, stream>>>(
        seq, eps_ih, mask_ih, w_ih, bias, xproj);
    k_recur<<<dim3(256), dim3(1024), 0, stream>>>(
        eps_hh, mask_hh, w_hh, xproj, hpk, out);
}

// Round 4
// 1831.588 us; speedup vs baseline: 4.4068x; 4.4068x over previous
//
#include <hip/hip_runtime.h>

#define NB 32
#define NT 512
#define NI 512
#define NH 512
#define NG 2048
#define GH (NG*NH)
#define BTH ((size_t)NB*NT*NH)   // 8388608
#define BH  (NB*NH)              // 16384

typedef unsigned int uint;
typedef unsigned long long u64;
typedef _Float16 v2h __attribute__((ext_vector_type(2)));
typedef _Float16 f16x4 __attribute__((ext_vector_type(4)));
typedef _Float16 f16x8 __attribute__((ext_vector_type(8)));
typedef float f32x4 __attribute__((ext_vector_type(4)));
union un8 { f16x4 h[2]; f16x8 v; };

// ---- ws layout (bytes) ----
#define OFF_XPROJ 0
#define SZ_XPROJ  ((size_t)NB*NT*NG*2)            // 64 MB  x_proj bf16 [B][T][G]
#define OFF_BIAS  (OFF_XPROJ + SZ_XPROJ)
#define SZ_BIAS   ((size_t)NB*NG*4)               // 256 KB fp32 bias [B][G]
#define OFF_HP    (OFF_BIAS + SZ_BIAS)
#define SZ_HP     ((size_t)2*NB*512*4)            // 128 KB tagged {tag16|f16} words, dbuf

__device__ __forceinline__ float bf2f(unsigned short u) {
    union { uint i; float f; } v; v.i = ((uint)u) << 16; return v.f;
}
__device__ __forceinline__ unsigned short f2bf(float f) {
    union { uint i; float f; } v; v.f = f;
    uint r = v.i + 0x7FFFu + ((v.i >> 16) & 1u);
    return (unsigned short)(r >> 16);
}
__device__ __forceinline__ uint pkf16(float a, float b) {
    auto p = __builtin_amdgcn_cvt_pkrtz(a, b);   // __fp16 ext_vector(2)
    return __builtin_bit_cast(uint, p);
}
__device__ __forceinline__ float dot2(uint wu, uint hu, float c) {
#if __has_builtin(__builtin_amdgcn_fdot2)
    return __builtin_amdgcn_fdot2(__builtin_bit_cast(v2h, wu),
                                  __builtin_bit_cast(v2h, hu), c, false);
#else
    v2h a = __builtin_bit_cast(v2h, wu), b = __builtin_bit_cast(v2h, hu);
    return c + (float)a[0] * (float)b[0] + (float)a[1] * (float)b[1];
#endif
}
// z = clip(1.2*sigmoid(1.5*(log(eps)-log(1-eps)+m)) - 0.1, 0, 1)
__device__ __forceinline__ float gate_z(float eps, float m) {
    float u = (__logf(eps) - __logf(1.0f - eps) + m) * 1.5f;
    float y = 1.0f / (1.0f + __expf(-u));
    float z = fmaf(y, 1.2f, -0.1f);
    return fminf(fmaxf(z, 0.0f), 1.0f);
}
__device__ __forceinline__ float sigmoidf_(float x) {
    return 1.0f / (1.0f + __expf(-x));
}
__device__ __forceinline__ float tanhf_(float x) {
    return 1.0f - 2.0f / (__expf(2.0f * x) + 1.0f);
}
// k-index XOR swizzle for xproj LDS tiles (rows stride 512 f16 = bank-degenerate)
__device__ __forceinline__ int kswz(int row, int k) {
    return k ^ ((row & 7) << 2);
}
// LDS swizzle for hsh pairs: 2-way max bank aliasing on 16B reads (free per m136)
__device__ __forceinline__ int hswz(int kg, int r, int u) {
    return (kg << 4) + (((r + (kg >> 1)) & 3) << 2) + u;
}
// DPP helpers (ctrl compile-time): row_ror:n = 0x120+n; quad_perm = 8-bit code
template<int CTRL>
__device__ __forceinline__ float dppadd(float v) {
    int s = __builtin_amdgcn_update_dpp(0, __builtin_bit_cast(int, v),
                                        CTRL, 0xF, 0xF, true);
    return v + __builtin_bit_cast(float, s);
}
template<int CTRL>
__device__ __forceinline__ float dppmov(float v) {
    int s = __builtin_amdgcn_update_dpp(0, __builtin_bit_cast(int, v),
                                        CTRL, 0xF, 0xF, true);
    return __builtin_bit_cast(float, s);
}

// ---------- bias[b][g] ----------
__global__ __launch_bounds__(256) void k_bias(
    const float* __restrict__ eb1, const float* __restrict__ eb2,
    const float* __restrict__ mb1, const float* __restrict__ mb2,
    const float* __restrict__ b1, const float* __restrict__ b2,
    float* __restrict__ bias) {
    int idx = blockIdx.x * 256 + threadIdx.x;
    int g = idx & (NG - 1);
    bias[idx] = gate_z(eb1[idx], mb1[g]) * b1[g] + gate_z(eb2[idx], mb2[g]) * b2[g];
}

// ---------- x_proj[b][t][g], f16 MFMA ----------
__global__ __launch_bounds__(512, 2) void k_xproj(
    const float* __restrict__ seq, const float* __restrict__ eps_ih,
    const float* __restrict__ mask_ih, const float* __restrict__ w_ih,
    const float* __restrict__ bias, unsigned short* __restrict__ xproj) {
    __shared__ _Float16 Wl[64][512];   // [g][k swizzled]  64 KB
    __shared__ _Float16 Al[64][512];   // [t][k swizzled]  64 KB
    int g0 = blockIdx.x << 6;
    int b  = blockIdx.y;
    int tid = threadIdx.x;
    int w = tid >> 6, lane = tid & 63;
    int lr = lane & 15, lg = lane >> 4;
    int mo = (w & 3) << 4, no = (w >> 2) << 5;

    // ---- stage gated W (once) ----
    {
        int g = tid >> 3, k0 = (tid & 7) << 6;
        size_t moff = (size_t)(g0 + g) * NI + k0;
        const float4* ep = (const float4*)(eps_ih + (size_t)b * GH + moff);
        const float4* mp = (const float4*)(mask_ih + moff);
        const float4* wp = (const float4*)(w_ih + moff);
#pragma unroll
        for (int q = 0; q < 16; ++q) {
            float4 e = ep[q], m = mp[q], wv = wp[q];
            f16x4 o;
            o[0] = (_Float16)(gate_z(e.x, m.x) * wv.x);
            o[1] = (_Float16)(gate_z(e.y, m.y) * wv.y);
            o[2] = (_Float16)(gate_z(e.z, m.z) * wv.z);
            o[3] = (_Float16)(gate_z(e.w, m.w) * wv.w);
            *(f16x4*)&Wl[g][kswz(g, k0 + (q << 2))] = o;
        }
    }

    float bs0 = bias[b * NG + g0 + no + lr];
    float bs1 = bias[b * NG + g0 + no + 16 + lr];
    int ra = mo + lr, rb0 = no + lr, rb1 = no + 16 + lr;

    for (int tc = 0; tc < NT; tc += 64) {
        // ---- stage A chunk (fp32 seq -> f16) ----
        {
            int r = tid >> 3, k0 = (tid & 7) << 6;
            const float4* sp = (const float4*)(seq + (size_t)(b * NT + tc + r) * NI + k0);
#pragma unroll
            for (int q = 0; q < 16; ++q) {
                float4 v = sp[q];
                f16x4 o;
                o[0] = (_Float16)v.x; o[1] = (_Float16)v.y;
                o[2] = (_Float16)v.z; o[3] = (_Float16)v.w;
                *(f16x4*)&Al[r][kswz(r, k0 + (q << 2))] = o;
            }
        }
        __syncthreads();

        f32x4 acc0 = {0.f, 0.f, 0.f, 0.f}, acc1 = {0.f, 0.f, 0.f, 0.f};
#pragma unroll
        for (int i0 = 0; i0 < NI; i0 += 32) {
            int k0 = i0 + (lg << 2);
            un8 a, b0, b1;
            a.h[0]  = *(const f16x4*)&Al[ra][kswz(ra, k0)];
            a.h[1]  = *(const f16x4*)&Al[ra][kswz(ra, k0 + 16)];
            b0.h[0] = *(const f16x4*)&Wl[rb0][kswz(rb0, k0)];
            b0.h[1] = *(const f16x4*)&Wl[rb0][kswz(rb0, k0 + 16)];
            b1.h[0] = *(const f16x4*)&Wl[rb1][kswz(rb1, k0)];
            b1.h[1] = *(const f16x4*)&Wl[rb1][kswz(rb1, k0 + 16)];
            acc0 = __builtin_amdgcn_mfma_f32_16x16x32_f16(a.v, b0.v, acc0, 0, 0, 0);
            acc1 = __builtin_amdgcn_mfma_f32_16x16x32_f16(a.v, b1.v, acc1, 0, 0, 0);
        }
        // ---- epilogue: +bias, bf16 store. C/D: col=lane&15, row=(lane>>4)*4+reg
#pragma unroll
        for (int r = 0; r < 4; ++r) {
            int t = tc + mo + (lg << 2) + r;
            unsigned short* op = xproj + ((size_t)(b * NT + t) << 11) + g0 + no + lr;
            op[0]  = f2bf(acc0[r] + bs0);
            op[16] = f2bf(acc1[r] + bs1);
        }
        __syncthreads();   // Al WAR guard before next chunk's staging
    }
}

// ---------- Persistent recurrence: weights resident in VGPRs ----------
// 256 blocks x 1024 threads, 1 block/CU. block bb: batch b=bb>>3, slice (bb&7)*64
// (round-2 proven mapping). Exchange: PURE agent-scope tagged atomics (round-2
// proven mechanism; round-3's sc0/L2 fast path REVERTED -- stale-L2-hit hazard).
// Word: {tag16 = t+1 | f16(h)} per j, double-buffered by parity. Producer: one
// relaxed agent-scope 32-bit store per leader lane. Consumer stager (tid<256):
// one relaxed agent-scope u64 load covering pair {2*tid, 2*tid+1}, exact-match
// both tags. Overwrite-safety: barrier orders produce(t+2) after stage(t+1), so
// a tag t+1 word can't be overwritten until every block consumed it (round-2 proof).
// Reduce: DPP row_ror butterfly (all 16 lanes end with all 4 gate sums).
// Barrier: raw s_barrier + lgkmcnt(0) only (no vmcnt drain of out/h stores).
__global__ __launch_bounds__(1024, 4) void k_recur(
    const float* __restrict__ eps, const float* __restrict__ mask,
    const float* __restrict__ w, const unsigned short* __restrict__ xproj,
    uint* __restrict__ hpk, float* __restrict__ out) {
    __shared__ uint hsh[2][256];   // double-buffered packed f16 h pairs (swizzled)
    int bb = blockIdx.x;
    int b = bb >> 3, slice = bb & 7;
    int tid = threadIdx.x;
    int wv = tid >> 6, lane = tid & 63;
    int jj = lane >> 4, kg = lane & 15;
    int j = (slice << 6) + (wv << 2) + jj;
    bool leader = (kg == 0);
    int gsel = kg & 3;

    // ---- one-time: load + gate + f16-pack weights into registers ----
    uint wreg[4][16];
#pragma unroll
    for (int q = 0; q < 4; ++q) {
        size_t off = (size_t)((q << 9) + j) * NH + (kg << 5);
        const float2* ep = (const float2*)(eps + (size_t)b * GH + off);
        const float2* mp = (const float2*)(mask + off);
        const float2* wp = (const float2*)(w + off);
#pragma unroll
        for (int u = 0; u < 16; ++u) {
            float2 e = ep[u], m = mp[u], ww = wp[u];
            wreg[q][u] = pkf16(gate_z(e.x, m.x) * ww.x,
                               gate_z(e.y, m.y) * ww.y);
        }
    }

    // prefetch xproj for t=0: lane kg<4 loads its own gate's addend
    float xp = 0.f;
    if (kg < 4) {
        const unsigned short* xq = xproj + ((size_t)(b * NT) << 11) + j + (gsel << 9);
        xp = bf2f(xq[0]);
    }

    float c = 0.0f;
    for (int t = 0; t < NT; ++t) {
        int par = t & 1;
        // ---- stage h: agent-scope poll of tagged word pair (round-2 mechanism)
        if (tid < 256 && !(t > 0 && (tid >> 5) == slice)) {
            const u64* src = (const u64*)(hpk + ((size_t)(par * NB + b) << 9)) + tid;
            uint lo, hi;
            for (;;) {
                u64 a = __hip_atomic_load(src, __ATOMIC_RELAXED,
                                          __HIP_MEMORY_SCOPE_AGENT);
                lo = (uint)a; hi = (uint)(a >> 32);
                if ((lo >> 16) == (uint)t && (hi >> 16) == (uint)t) break;
            }
            hsh[par][hswz(tid >> 4, (tid >> 2) & 3, tid & 3)] =
                (lo & 0xffffu) | (hi << 16);
        }
        // raw barrier: LDS ordering only, no vmcnt drain of out/h stores
        asm volatile("s_waitcnt lgkmcnt(0)\n\ts_barrier" ::: "memory");
        __builtin_amdgcn_sched_barrier(0);

        float a0 = 0.f, a1 = 0.f, a2 = 0.f, a3 = 0.f;
#pragma unroll
        for (int r = 0; r < 4; ++r) {
            uint4 hv = *(const uint4*)&hsh[par][hswz(kg, r, 0)];
            uint hu[4] = {hv.x, hv.y, hv.z, hv.w};
#pragma unroll
            for (int u = 0; u < 4; ++u) {
                a0 = dot2(wreg[0][(r << 2) + u], hu[u], a0);
                a1 = dot2(wreg[1][(r << 2) + u], hu[u], a1);
                a2 = dot2(wreg[2][(r << 2) + u], hu[u], a2);
                a3 = dot2(wreg[3][(r << 2) + u], hu[u], a3);
            }
        }
        // ---- DPP rotation butterfly within 16-lane rows: depth 4, VALU-rate.
        // After this every lane holds the full 16-lane sum of all 4 gates.
        a0 = dppadd<0x128>(a0); a1 = dppadd<0x128>(a1);   // row_ror:8
        a2 = dppadd<0x128>(a2); a3 = dppadd<0x128>(a3);
        a0 = dppadd<0x124>(a0); a1 = dppadd<0x124>(a1);   // row_ror:4
        a2 = dppadd<0x124>(a2); a3 = dppadd<0x124>(a3);
        a0 = dppadd<0x122>(a0); a1 = dppadd<0x122>(a1);   // row_ror:2
        a2 = dppadd<0x122>(a2); a3 = dppadd<0x122>(a3);
        a0 = dppadd<0x121>(a0); a1 = dppadd<0x121>(a1);   // row_ror:1
        a2 = dppadd<0x121>(a2); a3 = dppadd<0x121>(a3);
        // ---- lane-spread activation: lane kg&3 computes its gate's act ----
        float x = (gsel == 0 ? a0 : gsel == 1 ? a1 : gsel == 2 ? a2 : a3) + xp;
        float y = sigmoidf_(gsel == 2 ? 2.0f * x : x);
        float act = gsel == 2 ? fmaf(y, 2.0f, -1.0f) : y;
        // leader (kg=0) gathers f,g,o from its own quad via quad_perm DPP
        float af_ = dppmov<0x55>(act);   // quad_perm(1,1,1,1)
        float ag_ = dppmov<0xAA>(act);   // quad_perm(2,2,2,2)
        float ao_ = dppmov<0xFF>(act);   // quad_perm(3,3,3,3)
        if (leader) {
            c = fmaf(af_, c, act * ag_);   // act on leader = i-gate
            float h = ao_ * tanhf_(c);
            unsigned short hb = __builtin_bit_cast(unsigned short, (_Float16)h);
            uint word = ((uint)(t + 1) << 16) | (uint)hb;
            __hip_atomic_store(hpk + ((size_t)((par ^ 1) * NB + b) << 9) + j,
                               word, __ATOMIC_RELAXED, __HIP_MEMORY_SCOPE_AGENT);
            // local shortcut: own f16 straight into next LDS buffer
            int p = j >> 1;
            ((unsigned short*)&hsh[par ^ 1][hswz(p >> 4, (p >> 2) & 3, p & 3)])[j & 1] = hb;
            out[((size_t)(b * NT + t) << 9) + j] = h;
            if (t == NT - 1) {
                out[BTH + (size_t)(b << 9) + j] = h;
                out[BTH + BH + (size_t)(b << 9) + j] = c;
            }
        }
        // prefetch xproj for t+1 (off the critical path; absorbed by next poll)
        if (kg < 4 && t + 1 < NT) {
            const unsigned short* xq =
                xproj + ((size_t)(b * NT + t + 1) << 11) + j + (gsel << 9);
            xp = bf2f(xq[0]);
        }
    }
}

extern "C" void kernel_launch(void* const* d_in, const int* in_sizes, int n_in,
                              void* d_out, int out_size, void* d_ws, size_t ws_size,
                              hipStream_t stream) {
    const float* seq      = (const float*)d_in[0];
    const float* w_ih     = (const float*)d_in[1];
    const float* w_hh     = (const float*)d_in[2];
    const float* b_ih     = (const float*)d_in[3];
    const float* b_hh     = (const float*)d_in[4];
    const float* mask_ih  = (const float*)d_in[5];
    const float* mask_hh  = (const float*)d_in[6];
    const float* mask_bih = (const float*)d_in[7];
    const float* mask_bhh = (const float*)d_in[8];
    const float* eps_ih   = (const float*)d_in[9];
    const float* eps_hh   = (const float*)d_in[10];
    const float* eps_bih  = (const float*)d_in[11];
    const float* eps_bhh  = (const float*)d_in[12];

    char* ws = (char*)d_ws;
    unsigned short* xproj = (unsigned short*)(ws + OFF_XPROJ);
    float* bias  = (float*)(ws + OFF_BIAS);
    uint*  hpk   = (uint*)(ws + OFF_HP);
    float* out   = (float*)d_out;

    // zero BOTH parity buffers: t=0 expects tag 0 (h0=0); exact-match polling
    // means no stale tag from a previous run can ever false-trigger.
    (void)hipMemsetAsync(hpk, 0, SZ_HP, stream);

    k_bias<<<dim3(256), dim3(256), 0, stream>>>(eps_bih, eps_bhh, mask_bih, mask_bhh,
                                                b_ih, b_hh, bias);
    k_xproj<<<dim3(NG / 64, NB), dim3(512), 0, stream>>>(
        seq, eps_ih, mask_ih, w_ih, bias, xproj);
    k_recur<<<dim3(256), dim3(1024), 0, stream>>>(
        eps_hh, mask_hh, w_hh, xproj, hpk, out);
}